// Round 12
// baseline (405.693 us; speedup 1.0000x reference)
//
#include <hip/hip_runtime.h>
#include <hip/hip_bf16.h>

#define DDIM 1024
#define SLEN 2048
#define NTOK 8192
#define MLPD 4096

typedef float f32x4 __attribute__((ext_vector_type(4)));
typedef __bf16 bf16x8 __attribute__((ext_vector_type(8)));

__device__ __forceinline__ void async16(void* lds, const void* g) {
  __builtin_amdgcn_global_load_lds(
      (__attribute__((address_space(1))) void*)g,
      (__attribute__((address_space(3))) void*)lds, 16, 0, 0);
}

template <int N> struct VMC { static constexpr int v = N; };

// ---------------------------------------------------------------------------
// prep: router logits + mask + probs, causal depthwise conv (k=3), x -> bf16
// ---------------------------------------------------------------------------
__global__ __launch_bounds__(256) void prep_kernel(
    const float* __restrict__ x, const float* __restrict__ gate_w,
    const float* __restrict__ gate_b, const float* __restrict__ conv_w,
    const float* __restrict__ conv_b, __bf16* __restrict__ xb,
    __bf16* __restrict__ xcb, float* __restrict__ maskp,
    float* __restrict__ probsp) {
  const int tok = blockIdx.x, t = threadIdx.x;
  const int s = tok & (SLEN - 1);
  const float* xr = x + (size_t)tok * DDIM;
  float4 v = ((const float4*)xr)[t];
  float4 g = ((const float4*)gate_w)[t];
  float part = v.x * g.x + v.y * g.y + v.z * g.z + v.w * g.w;
#pragma unroll
  for (int d = 32; d; d >>= 1) part += __shfl_down(part, d);
  __shared__ float ws4[4];
  const int lane = t & 63, w = t >> 6;
  if (lane == 0) ws4[w] = part;
  __syncthreads();
  if (t == 0) {
    float logit = ws4[0] + ws4[1] + ws4[2] + ws4[3] + gate_b[0];
    float prob = 1.f / (1.f + __expf(-logit));
    probsp[tok] = prob;
    maskp[tok] = prob > 0.5f ? 1.f : 0.f;
  }
  union { ushort4 u; __bf16 b[4]; } xo;
  xo.b[0] = (__bf16)v.x; xo.b[1] = (__bf16)v.y;
  xo.b[2] = (__bf16)v.z; xo.b[3] = (__bf16)v.w;
  ((ushort4*)(xb + (size_t)tok * DDIM))[t] = xo.u;
  float4 zero4 = {0.f, 0.f, 0.f, 0.f};
  float4 m1 = (s >= 1) ? ((const float4*)(xr - DDIM))[t] : zero4;
  float4 m2 = (s >= 2) ? ((const float4*)(xr - 2 * DDIM))[t] : zero4;
  int d0 = t * 4;
  float vv[4] = {v.x, v.y, v.z, v.w};
  float a1[4] = {m1.x, m1.y, m1.z, m1.w};
  float a2[4] = {m2.x, m2.y, m2.z, m2.w};
  union { ushort4 u; __bf16 b[4]; } co;
#pragma unroll
  for (int i = 0; i < 4; ++i) {
    float c0 = conv_w[(d0 + i) * 3 + 0];
    float c1 = conv_w[(d0 + i) * 3 + 1];
    float c2 = conv_w[(d0 + i) * 3 + 2];
    float r = a2[i] * c0 + a1[i] * c1 + vv[i] * c2 + conv_b[d0 + i];
    co.b[i] = (__bf16)r;
  }
  ((ushort4*)(xcb + (size_t)tok * DDIM))[t] = co.u;
}

// ---------------------------------------------------------------------------
// transposed cast: src [K][N] f32 -> dst [N][K] bf16
// ---------------------------------------------------------------------------
__global__ __launch_bounds__(256) void tcast_kernel(const float* __restrict__ src,
                                                    __bf16* __restrict__ dst,
                                                    int K, int N) {
  __shared__ __bf16 tile[64][65];
  const int n0 = blockIdx.x * 64, k0 = blockIdx.y * 64;
  const int t = threadIdx.x;
  const int cr = (t & 15) * 4;
#pragma unroll
  for (int i = 0; i < 4; ++i) {
    int rr = (t >> 4) + i * 16;
    float4 v = *(const float4*)(src + (size_t)(k0 + rr) * N + n0 + cr);
    tile[rr][cr + 0] = (__bf16)v.x; tile[rr][cr + 1] = (__bf16)v.y;
    tile[rr][cr + 2] = (__bf16)v.z; tile[rr][cr + 3] = (__bf16)v.w;
  }
  __syncthreads();
#pragma unroll
  for (int i = 0; i < 2; ++i) {
    int c = t + i * 256;
    int nl = c >> 3, koff = (c & 7) * 8;
    union { uint4 u; __bf16 b[8]; } o;
#pragma unroll
    for (int j = 0; j < 8; ++j) o.b[j] = tile[koff + j][nl];
    *(uint4*)(dst + (size_t)(n0 + nl) * K + k0 + koff) = o.u;
  }
}

// ---------------------------------------------------------------------------
// 256x256 pipelined GEMM: C = A[M,K] * Bt[N,K]^T, bf16 in, fp32 acc.
// 512 threads = 8 waves (2M x 4N), per-wave out 128x64, BK=32.
// Ring of 4 LDS buffers x 32KB (A 16KB + B 16KB), prefetch 3 tiles ahead.
// Per tile: stage(t+3); s_waitcnt vmcnt(12) [counted, never 0 in main loop];
// s_barrier; 12x ds_read_b128; 32 MFMA (setprio); s_barrier. Tail peeled
// with vmcnt(8)/(4)/(0). Loads stay in flight across barriers (T4).
// LDS tile layout: [row'=Mrow>>1][ (Mrow&1)*32 + kk ] bf16, 16B-unit XOR
// swizzle u ^= row'&7 (2-way bank conflicts only, i.e. free).
// EPI: 0 = bf16 store; 1 = bf16 relu(v+bias).
// ---------------------------------------------------------------------------
template <int EPI>
__global__ __launch_bounds__(512, 2) void gemm256p(
    const __bf16* __restrict__ A, const __bf16* __restrict__ Bt,
    const float* __restrict__ bias, __bf16* __restrict__ Cb,
    int M, int N, int K) {
  extern __shared__ char sm[];
  const int t = threadIdx.x, lane = t & 63, w = t >> 6;
  const int c = lane & 15, g = lane >> 4;
  const int nwg = gridDim.x * gridDim.y;
  const int wgid = blockIdx.y * gridDim.x + blockIdx.x;
  const int swz = (wgid & 7) * (nwg >> 3) + (wgid >> 3);
  const int m0 = (swz / gridDim.x) * 256, n0 = (swz % gridDim.x) * 256;
  const int wm = (w >> 2) * 128, wn = (w & 3) * 64;

  f32x4 acc[8][4] = {};
  const int nk = K >> 5;

  // stage tile kt into ring buffer `buf` (4 loads/thread: 2 A + 2 B)
  auto stage = [&](int buf, int kt) {
    const int k0 = kt << 5;
    char* base = sm + buf * 32768;
#pragma unroll
    for (int r = 0; r < 2; ++r) {
      int o = ((r * 8 + w) << 10) + (lane << 4);
      int rp = o >> 7;               // row' (2 M-rows packed per 128B)
      int u = (o >> 4) & 7;          // physical 16B unit
      int l = u ^ (rp & 7);          // logical unit
      int mr = rp * 2 + (l >> 2);    // M row within tile
      int kk = (l & 3) * 8;          // K offset
      async16(base + o, A + (size_t)(m0 + mr) * K + k0 + kk);
      async16(base + 16384 + o, Bt + (size_t)(n0 + mr) * K + k0 + kk);
    }
  };

  auto body = [&](auto vmc, int tt, bool dostage) {
    if (dostage) stage((tt + 3) & 3, tt + 3);
    asm volatile("s_waitcnt vmcnt(%0)" ::"n"(decltype(vmc)::v) : "memory");
    __builtin_amdgcn_s_barrier();
    asm volatile("" ::: "memory");
    const char* Ab = sm + (tt & 3) * 32768;
    const char* Bb = Ab + 16384;
    bf16x8 aq[8], bq[4];
#pragma unroll
    for (int nt = 0; nt < 4; ++nt) {
      int row = wn + nt * 16 + c;
      int rp = row >> 1;
      int u = ((row & 1) * 4 + g) ^ (rp & 7);
      bq[nt] = *(const bf16x8*)(Bb + rp * 128 + u * 16);
    }
#pragma unroll
    for (int i = 0; i < 8; ++i) {
      int row = wm + i * 16 + c;
      int rp = row >> 1;
      int u = ((row & 1) * 4 + g) ^ (rp & 7);
      aq[i] = *(const bf16x8*)(Ab + rp * 128 + u * 16);
    }
    __builtin_amdgcn_s_setprio(1);
#pragma unroll
    for (int i = 0; i < 8; ++i)
#pragma unroll
      for (int nt = 0; nt < 4; ++nt)
        acc[i][nt] = __builtin_amdgcn_mfma_f32_16x16x32_bf16(
            aq[i], bq[nt], acc[i][nt], 0, 0, 0);
    __builtin_amdgcn_s_setprio(0);
    __builtin_amdgcn_s_barrier();
    asm volatile("" ::: "memory");
  };

  // prologue: 3 tiles in flight
  stage(0, 0);
  stage(1, 1);
  stage(2, 2);
  int tt = 0;
  for (; tt < nk - 3; ++tt) body(VMC<12>{}, tt, true);
  body(VMC<8>{}, tt, false); ++tt;
  body(VMC<4>{}, tt, false); ++tt;
  body(VMC<0>{}, tt, false);

  // epilogue
#pragma unroll
  for (int i = 0; i < 8; ++i)
#pragma unroll
    for (int nt = 0; nt < 4; ++nt)
#pragma unroll
      for (int r = 0; r < 4; ++r) {
        int row = m0 + wm + i * 16 + g * 4 + r;
        int col = n0 + wn + nt * 16 + c;
        float v = acc[i][nt][r];
        size_t idx = (size_t)row * N + col;
        if constexpr (EPI == 0) {
          Cb[idx] = (__bf16)v;
        } else {
          v += bias[col];
          Cb[idx] = (__bf16)fmaxf(v, 0.f);
        }
      }
}

// ---------------------------------------------------------------------------
// GEMM 128x128 (kept for the 128-block-grid cases MLP2/WO): C = A * Bt^T.
// EPI: 2 = f32 out = xres + v + bias; 3 = f32 out += mask[row]*v
// ---------------------------------------------------------------------------
template <int EPI>
__global__ __launch_bounds__(256, 3) void gemm_bt(
    const __bf16* __restrict__ A, const __bf16* __restrict__ Bt,
    const float* __restrict__ bias, const float* __restrict__ xres,
    const float* __restrict__ maskp, __bf16* __restrict__ Cb,
    float* __restrict__ Cf, int M, int N, int K) {
  __shared__ char smem[32768];
  char* As = smem;
  char* Bs = smem + 16384;
  const int t = threadIdx.x, lane = t & 63, w = t >> 6;
  const int nwg = gridDim.x * gridDim.y;
  const int wgid = blockIdx.y * gridDim.x + blockIdx.x;
  const int swz = (wgid & 7) * (nwg >> 3) + (wgid >> 3);
  const int m0 = (swz / gridDim.x) * 128, n0 = (swz % gridDim.x) * 128;
  const int wm = (w >> 1) * 64, wn = (w & 1) * 64;
  f32x4 acc[4][4] = {};
  const int nk = K >> 6;
  for (int kt = 0; kt < nk; ++kt) {
    const int k0 = kt << 6;
#pragma unroll
    for (int rd = 0; rd < 4; ++rd) {
      int o = ((rd * 4 + w) << 10) + (lane << 4);
      int row = o >> 7;
      int us = ((o >> 4) & 7) ^ (row & 7);
      async16(As + o, A + (size_t)(m0 + row) * K + k0 + us * 8);
      async16(Bs + o, Bt + (size_t)(n0 + row) * K + k0 + us * 8);
    }
    __syncthreads();
#pragma unroll
    for (int ks = 0; ks < 2; ++ks) {
      bf16x8 af[4], bfr[4];
#pragma unroll
      for (int mt = 0; mt < 4; ++mt) {
        int row = wm + mt * 16 + (lane & 15);
        int u = (ks * 4 + (lane >> 4)) ^ (row & 7);
        af[mt] = *(const bf16x8*)(As + row * 128 + u * 16);
      }
#pragma unroll
      for (int nt = 0; nt < 4; ++nt) {
        int row = wn + nt * 16 + (lane & 15);
        int u = (ks * 4 + (lane >> 4)) ^ (row & 7);
        bfr[nt] = *(const bf16x8*)(Bs + row * 128 + u * 16);
      }
#pragma unroll
      for (int mt = 0; mt < 4; ++mt)
#pragma unroll
        for (int nt = 0; nt < 4; ++nt)
          acc[mt][nt] = __builtin_amdgcn_mfma_f32_16x16x32_bf16(
              af[mt], bfr[nt], acc[mt][nt], 0, 0, 0);
    }
    __syncthreads();
  }
#pragma unroll
  for (int mt = 0; mt < 4; ++mt)
#pragma unroll
    for (int nt = 0; nt < 4; ++nt)
#pragma unroll
      for (int r = 0; r < 4; ++r) {
        int row = m0 + wm + mt * 16 + ((lane >> 4) << 2) + r;
        int col = n0 + wn + nt * 16 + (lane & 15);
        float v = acc[mt][nt][r];
        size_t idx = (size_t)row * N + col;
        if constexpr (EPI == 2) {
          Cf[idx] = xres[idx] + v + bias[col];
        } else {
          Cf[idx] += maskp[row] * v;
        }
      }
}

// ---------------------------------------------------------------------------
// RoPE in-place on fused qkv [8192][3072]. 32 distinct trig pairs per token.
// ---------------------------------------------------------------------------
__global__ __launch_bounds__(256) void rope_kernel(__bf16* __restrict__ qkv) {
  __shared__ float snv[32], csv[32];
  const int tok = blockIdx.x, t = threadIdx.x;
  const int s = tok & (SLEN - 1);
  if (t < 32) {
    float invf = __builtin_amdgcn_exp2f(-(float)t * (13.28771238f / 32.f));
    float fr = (float)s * invf;
    snv[t] = sinf(fr);
    csv[t] = cosf(fr);
  }
  __syncthreads();
#pragma unroll
  for (int pp = 0; pp < 2; ++pp) {
    int p = t + pp * 256;
    int h = p >> 5, i = p & 31;
    float sn = snv[i], cs = csv[i];
    __bf16* qp = qkv + (size_t)tok * 3072 + h * 64 + i;
    float xq = (float)qp[0], yq = (float)qp[32];
    qp[0] = (__bf16)(xq * cs - yq * sn);
    qp[32] = (__bf16)(yq * cs + xq * sn);
    __bf16* kp = qp + 1024;
    float xk = (float)kp[0], yk = (float)kp[32];
    kp[0] = (__bf16)(xk * cs - yk * sn);
    kp[32] = (__bf16)(yk * cs + xk * sn);
  }
}

// ---------------------------------------------------------------------------
// V scatter: regs -> swizzled Vt[d][kj] LDS
// ---------------------------------------------------------------------------
__device__ __forceinline__ void scatterV(char* Vdst, int w, int lane,
                                         float4 va, float4 vb) {
  union { float4 f; __bf16 bv[8]; } u0, u1;
  u0.f = va; u1.f = vb;
#pragma unroll
  for (int j = 0; j < 8; ++j) {
    int d = w * 8 + j;
    int by = d * 128 + (((lane >> 3) ^ (d & 7)) << 4) + ((lane & 7) << 1);
    *(__bf16*)(Vdst + by) = u0.bv[j];
    int d2 = d + 32;
    int by2 = d2 * 128 + (((lane >> 3) ^ (d2 & 7)) << 4) + ((lane & 7) << 1);
    *(__bf16*)(Vdst + by2) = u1.bv[j];
  }
}

// ---------------------------------------------------------------------------
// Flash attention, causal, swapped QK^T (S^T = K·Q^T), in-lane softmax.
// Uniform q-tile pairs, 512 blocks all resident, 32KB LDS, (256,3).
// ---------------------------------------------------------------------------
__global__ __launch_bounds__(256, 3) void attn_kernel(const __bf16* __restrict__ qkv,
                                                      __bf16* __restrict__ ctx) {
  __shared__ char sm[32768];
  const int t = threadIdx.x, lane = t & 63, w = t >> 6;
  const int c = lane & 15, g = lane >> 4, g4 = g * 4;
  const int bh = blockIdx.y, h = bh & 15, b = bh >> 4;
  const size_t tokbase = (size_t)b * SLEN;
  const __bf16* qg = qkv + tokbase * 3072 + h * 64;
  const __bf16* kg = qg + 1024;
  const __bf16* vg = qg + 2048;
  const float SCL = 0.125f * 1.44269504f;  // 1/sqrt(64) * log2(e)
  char* Ps = sm + (w << 12);
  char* Ks = sm + 16384;
  char* Vs = sm + 24576;

  for (int ph = 0; ph < 2; ++ph) {
    const int qt = ph == 0 ? (int)blockIdx.x : 15 - (int)blockIdx.x;
    const int q0 = qt * 128;
#pragma unroll
    for (int rd = 0; rd < 4; ++rd) {
      int o = ((rd * 4 + w) << 10) + (lane << 4);
      int row = o >> 7;
      int us = ((o >> 4) & 7) ^ (row & 7);
      async16(sm + o, qg + (size_t)(q0 + row) * 3072 + us * 8);
    }
    __syncthreads();
    bf16x8 qb[2][2];
#pragma unroll
    for (int mt = 0; mt < 2; ++mt)
#pragma unroll
      for (int ks = 0; ks < 2; ++ks) {
        int row = w * 32 + mt * 16 + c;
        int u = (ks * 4 + g) ^ (row & 7);
        qb[mt][ks] = *(const bf16x8*)(sm + row * 128 + u * 16);
      }

    float m_run[2] = {-1e30f, -1e30f}, l_run[2] = {0.f, 0.f};
    f32x4 o_acc[2][4] = {};
    const int nkt = (q0 + 128) >> 6;
    const int wrow0 = q0 + w * 32;

    for (int kt = 0; kt < nkt; ++kt) {
      const int k0 = kt << 6;
#pragma unroll
      for (int rd = 0; rd < 2; ++rd) {
        int o = ((rd * 4 + w) << 10) + (lane << 4);
        int row = o >> 7;
        int us = ((o >> 4) & 7) ^ (row & 7);
        async16(Ks + o, kg + (size_t)(k0 + row) * 3072 + us * 8);
      }
      {
        float4 va = *(const float4*)(vg + (size_t)(k0 + lane) * 3072 + w * 8);
        float4 vb2 = *(const float4*)(vg + (size_t)(k0 + lane) * 3072 + w * 8 + 32);
        scatterV(Vs, w, lane, va, vb2);
      }
      __syncthreads();
      if (k0 <= wrow0 + 31) {
        f32x4 st[4][2] = {};
        __builtin_amdgcn_s_setprio(1);
#pragma unroll
        for (int ks = 0; ks < 2; ++ks) {
          bf16x8 ka[4];
#pragma unroll
          for (int nt = 0; nt < 4; ++nt) {
            int row = nt * 16 + c;
            int u = (ks * 4 + g) ^ (row & 7);
            ka[nt] = *(const bf16x8*)(Ks + row * 128 + u * 16);
          }
#pragma unroll
          for (int nt = 0; nt < 4; ++nt)
#pragma unroll
            for (int mt = 0; mt < 2; ++mt)
              st[nt][mt] = __builtin_amdgcn_mfma_f32_16x16x32_bf16(
                  ka[nt], qb[mt][ks], st[nt][mt], 0, 0, 0);
        }
        __builtin_amdgcn_s_setprio(0);
        const bool needmask = (k0 + 63) > wrow0;
#pragma unroll
        for (int mt = 0; mt < 2; ++mt) {
          float mx = -1e30f;
          if (needmask) {
            int qglob = wrow0 + mt * 16 + c;
#pragma unroll
            for (int nt = 0; nt < 4; ++nt)
#pragma unroll
              for (int r = 0; r < 4; ++r) {
                float sv = st[nt][mt][r] * SCL;
                if (k0 + nt * 16 + g4 + r > qglob) sv = -1e30f;
                st[nt][mt][r] = sv;
                mx = fmaxf(mx, sv);
              }
          } else {
#pragma unroll
            for (int nt = 0; nt < 4; ++nt)
#pragma unroll
              for (int r = 0; r < 4; ++r) {
                float sv = st[nt][mt][r] * SCL;
                st[nt][mt][r] = sv;
                mx = fmaxf(mx, sv);
              }
          }
          mx = fmaxf(mx, __shfl_xor(mx, 16));
          mx = fmaxf(mx, __shfl_xor(mx, 32));
          const bool skip = __all(mx - m_run[mt] <= 8.f) != 0;
          float mnew = skip ? m_run[mt] : fmaxf(m_run[mt], mx);
          float rs = 0.f;
#pragma unroll
          for (int nt = 0; nt < 4; ++nt)
#pragma unroll
            for (int r = 0; r < 4; ++r) {
              float p = __builtin_amdgcn_exp2f(st[nt][mt][r] - mnew);
              st[nt][mt][r] = p;
              rs += p;
            }
          rs += __shfl_xor(rs, 16);
          rs += __shfl_xor(rs, 32);
          if (skip) {
            l_run[mt] += rs;
          } else {
            float fac = __builtin_amdgcn_exp2f(m_run[mt] - mnew);
            m_run[mt] = mnew;
            l_run[mt] = l_run[mt] * fac + rs;
#pragma unroll
            for (int r = 0; r < 4; ++r) {
              float fr = __shfl(fac, g * 20 + r);
#pragma unroll
              for (int dt = 0; dt < 4; ++dt) o_acc[mt][dt][r] *= fr;
            }
          }
          int rowq = mt * 16 + c;
          int rbase = rowq * 128 + 8 * (g & 1);
#pragma unroll
          for (int nt = 0; nt < 4; ++nt) {
            int us = (2 * nt + (g >> 1)) ^ (c & 7);
            union { uint2 v; __bf16 bb[4]; } pp;
            pp.bb[0] = (__bf16)st[nt][mt][0]; pp.bb[1] = (__bf16)st[nt][mt][1];
            pp.bb[2] = (__bf16)st[nt][mt][2]; pp.bb[3] = (__bf16)st[nt][mt][3];
            *(uint2*)(Ps + rbase + us * 16) = pp.v;
          }
        }
        __builtin_amdgcn_s_setprio(1);
#pragma unroll
        for (int ks = 0; ks < 2; ++ks) {
          bf16x8 pa[2], vb[4];
#pragma unroll
          for (int mt = 0; mt < 2; ++mt) {
            int row = mt * 16 + c;
            int u = (ks * 4 + g) ^ (row & 7);
            pa[mt] = *(const bf16x8*)(Ps + row * 128 + u * 16);
          }
#pragma unroll
          for (int dt = 0; dt < 4; ++dt) {
            int row = dt * 16 + c;
            int u = (ks * 4 + g) ^ (row & 7);
            vb[dt] = *(const bf16x8*)(Vs + row * 128 + u * 16);
          }
#pragma unroll
          for (int mt = 0; mt < 2; ++mt)
#pragma unroll
            for (int dt = 0; dt < 4; ++dt)
              o_acc[mt][dt] = __builtin_amdgcn_mfma_f32_16x16x32_bf16(
                  pa[mt], vb[dt], o_acc[mt][dt], 0, 0, 0);
        }
        __builtin_amdgcn_s_setprio(0);
      }
      __syncthreads();
    }
#pragma unroll
    for (int mt = 0; mt < 2; ++mt)
#pragma unroll
      for (int r = 0; r < 4; ++r) {
        float lr = __shfl(l_run[mt], g * 20 + r);
        float inv = 1.f / lr;
        int tokr = q0 + w * 32 + mt * 16 + g4 + r;
#pragma unroll
        for (int dt = 0; dt < 4; ++dt) {
          int d = dt * 16 + c;
          ctx[(tokbase + tokr) * DDIM + h * 64 + d] =
              (__bf16)(o_acc[mt][dt][r] * inv);
        }
      }
  }
}

// ---------------------------------------------------------------------------
// aux loss: (mean(probs) - 0.2)^2
// ---------------------------------------------------------------------------
__global__ __launch_bounds__(256) void aux_kernel(const float* __restrict__ probsp,
                                                  float* __restrict__ outp) {
  const int t = threadIdx.x;
  float sum = 0.f;
  for (int i = t; i < NTOK; i += 256) sum += probsp[i];
#pragma unroll
  for (int d = 32; d; d >>= 1) sum += __shfl_down(sum, d);
  __shared__ float ws4[4];
  if ((t & 63) == 0) ws4[t >> 6] = sum;
  __syncthreads();
  if (t == 0) {
    float m = (ws4[0] + ws4[1] + ws4[2] + ws4[3]) * (1.f / NTOK) - 0.2f;
    outp[0] = m * m;
  }
}

// ---------------------------------------------------------------------------
extern "C" void kernel_launch(void* const* d_in, const int* in_sizes, int n_in,
                              void* d_out, int out_size, void* d_ws, size_t ws_size,
                              hipStream_t stream) {
  const float* x      = (const float*)d_in[0];
  const float* gate_w = (const float*)d_in[1];
  const float* gate_b = (const float*)d_in[2];
  const float* wq     = (const float*)d_in[3];
  const float* wk     = (const float*)d_in[4];
  const float* wv     = (const float*)d_in[5];
  const float* wo     = (const float*)d_in[6];
  const float* conv_w = (const float*)d_in[7];
  const float* conv_b = (const float*)d_in[8];
  const float* mlp_w1 = (const float*)d_in[9];
  const float* mlp_b1 = (const float*)d_in[10];
  const float* mlp_w2 = (const float*)d_in[11];
  const float* mlp_b2 = (const float*)d_in[12];
  float* out = (float*)d_out;

  char* ws = (char*)d_ws;
  const size_t MB = 1ull << 20;
  __bf16* xb     = (__bf16*)(ws + 0);
  __bf16* xcb    = (__bf16*)(ws + 16 * MB);
  __bf16* ctx    = (__bf16*)(ws + 16 * MB);    // overlays xcb
  __bf16* wqkv_t = (__bf16*)(ws + 32 * MB);
  __bf16* wo_t   = (__bf16*)(ws + 38 * MB);
  __bf16* w1_t   = (__bf16*)(ws + 40 * MB);
  __bf16* w2_t   = (__bf16*)(ws + 48 * MB);
  float*  maskp  = (float*)(ws + 56 * MB);
  float*  probsp = (float*)(ws + 56 * MB + 65536);
  __bf16* h1     = (__bf16*)(ws + 57 * MB);
  __bf16* qkv    = (__bf16*)(ws + 57 * MB);    // overlays h1

  prep_kernel<<<NTOK, 256, 0, stream>>>(x, gate_w, gate_b, conv_w, conv_b,
                                        xb, xcb, maskp, probsp);
  tcast_kernel<<<dim3(16, 16), 256, 0, stream>>>(wq, wqkv_t, 1024, 1024);
  tcast_kernel<<<dim3(16, 16), 256, 0, stream>>>(wk, wqkv_t + 1024 * 1024, 1024, 1024);
  tcast_kernel<<<dim3(16, 16), 256, 0, stream>>>(wv, wqkv_t + 2048 * 1024, 1024, 1024);
  tcast_kernel<<<dim3(16, 16), 256, 0, stream>>>(wo, wo_t, 1024, 1024);
  tcast_kernel<<<dim3(64, 16), 256, 0, stream>>>(mlp_w1, w1_t, 1024, 4096);
  tcast_kernel<<<dim3(16, 64), 256, 0, stream>>>(mlp_w2, w2_t, 4096, 1024);

  // Reflexive (MLP) stream first so h1 region can be reused by qkv.
  gemm256p<1><<<dim3(16, 32), 512, 131072, stream>>>(xcb, w1_t, mlp_b1, h1,
                                                     NTOK, MLPD, DDIM);
  gemm_bt<2><<<dim3(8, 64), 256, 0, stream>>>(h1, w2_t, mlp_b2, x, nullptr,
                                              nullptr, out, NTOK, DDIM, MLPD);
  // Contextual stream.
  gemm256p<0><<<dim3(12, 32), 512, 131072, stream>>>(xb, wqkv_t, nullptr, qkv,
                                                     NTOK, 3072, DDIM);
  rope_kernel<<<NTOK, 256, 0, stream>>>(qkv);
  attn_kernel<<<dim3(8, 64), 256, 0, stream>>>(qkv, ctx);
  gemm_bt<3><<<dim3(8, 64), 256, 0, stream>>>(ctx, wo_t, nullptr, nullptr, maskp,
                                              nullptr, out, NTOK, DDIM, DDIM);
  aux_kernel<<<1, 256, 0, stream>>>(probsp, out + (size_t)(out_size - 1));
}

// Round 13
// 393.523 us; speedup vs baseline: 1.0309x; 1.0309x over previous
//
#include <hip/hip_runtime.h>
#include <hip/hip_bf16.h>

#define DDIM 1024
#define SLEN 2048
#define NTOK 8192
#define MLPD 4096

typedef float f32x4 __attribute__((ext_vector_type(4)));
typedef __bf16 bf16x8 __attribute__((ext_vector_type(8)));

__device__ __forceinline__ void async16(void* lds, const void* g) {
  __builtin_amdgcn_global_load_lds(
      (__attribute__((address_space(1))) void*)g,
      (__attribute__((address_space(3))) void*)lds, 16, 0, 0);
}

template <int N> struct VMC { static constexpr int v = N; };

// ---------------------------------------------------------------------------
// prep: router logits + mask + probs, causal depthwise conv (k=3), x -> bf16
// ---------------------------------------------------------------------------
__global__ __launch_bounds__(256) void prep_kernel(
    const float* __restrict__ x, const float* __restrict__ gate_w,
    const float* __restrict__ gate_b, const float* __restrict__ conv_w,
    const float* __restrict__ conv_b, __bf16* __restrict__ xb,
    __bf16* __restrict__ xcb, float* __restrict__ maskp,
    float* __restrict__ probsp) {
  const int tok = blockIdx.x, t = threadIdx.x;
  const int s = tok & (SLEN - 1);
  const float* xr = x + (size_t)tok * DDIM;
  float4 v = ((const float4*)xr)[t];
  float4 g = ((const float4*)gate_w)[t];
  float part = v.x * g.x + v.y * g.y + v.z * g.z + v.w * g.w;
#pragma unroll
  for (int d = 32; d; d >>= 1) part += __shfl_down(part, d);
  __shared__ float ws4[4];
  const int lane = t & 63, w = t >> 6;
  if (lane == 0) ws4[w] = part;
  __syncthreads();
  if (t == 0) {
    float logit = ws4[0] + ws4[1] + ws4[2] + ws4[3] + gate_b[0];
    float prob = 1.f / (1.f + __expf(-logit));
    probsp[tok] = prob;
    maskp[tok] = prob > 0.5f ? 1.f : 0.f;
  }
  union { ushort4 u; __bf16 b[4]; } xo;
  xo.b[0] = (__bf16)v.x; xo.b[1] = (__bf16)v.y;
  xo.b[2] = (__bf16)v.z; xo.b[3] = (__bf16)v.w;
  ((ushort4*)(xb + (size_t)tok * DDIM))[t] = xo.u;
  float4 zero4 = {0.f, 0.f, 0.f, 0.f};
  float4 m1 = (s >= 1) ? ((const float4*)(xr - DDIM))[t] : zero4;
  float4 m2 = (s >= 2) ? ((const float4*)(xr - 2 * DDIM))[t] : zero4;
  int d0 = t * 4;
  float vv[4] = {v.x, v.y, v.z, v.w};
  float a1[4] = {m1.x, m1.y, m1.z, m1.w};
  float a2[4] = {m2.x, m2.y, m2.z, m2.w};
  union { ushort4 u; __bf16 b[4]; } co;
#pragma unroll
  for (int i = 0; i < 4; ++i) {
    float c0 = conv_w[(d0 + i) * 3 + 0];
    float c1 = conv_w[(d0 + i) * 3 + 1];
    float c2 = conv_w[(d0 + i) * 3 + 2];
    float r = a2[i] * c0 + a1[i] * c1 + vv[i] * c2 + conv_b[d0 + i];
    co.b[i] = (__bf16)r;
  }
  ((ushort4*)(xcb + (size_t)tok * DDIM))[t] = co.u;
}

// ---------------------------------------------------------------------------
// RoPE trig table: tab[s][i] = (cos(s*invf(i)), sin(s*invf(i))), s<2048, i<32
// ---------------------------------------------------------------------------
__global__ __launch_bounds__(256) void tabgen_kernel(float2* __restrict__ tab) {
  const int idx = blockIdx.x * 256 + threadIdx.x;  // 65536 total
  const int s = idx >> 5, i = idx & 31;
  float invf = __builtin_amdgcn_exp2f(-(float)i * (13.28771238f / 32.f));
  float fr = (float)s * invf;
  tab[idx] = make_float2(cosf(fr), sinf(fr));
}

// ---------------------------------------------------------------------------
// transposed cast: src [K][N] f32 -> dst [N][K] bf16
// ---------------------------------------------------------------------------
__global__ __launch_bounds__(256) void tcast_kernel(const float* __restrict__ src,
                                                    __bf16* __restrict__ dst,
                                                    int K, int N) {
  __shared__ __bf16 tile[64][65];
  const int n0 = blockIdx.x * 64, k0 = blockIdx.y * 64;
  const int t = threadIdx.x;
  const int cr = (t & 15) * 4;
#pragma unroll
  for (int i = 0; i < 4; ++i) {
    int rr = (t >> 4) + i * 16;
    float4 v = *(const float4*)(src + (size_t)(k0 + rr) * N + n0 + cr);
    tile[rr][cr + 0] = (__bf16)v.x; tile[rr][cr + 1] = (__bf16)v.y;
    tile[rr][cr + 2] = (__bf16)v.z; tile[rr][cr + 3] = (__bf16)v.w;
  }
  __syncthreads();
#pragma unroll
  for (int i = 0; i < 2; ++i) {
    int c = t + i * 256;
    int nl = c >> 3, koff = (c & 7) * 8;
    union { uint4 u; __bf16 b[8]; } o;
#pragma unroll
    for (int j = 0; j < 8; ++j) o.b[j] = tile[koff + j][nl];
    *(uint4*)(dst + (size_t)(n0 + nl) * K + k0 + koff) = o.u;
  }
}

// ---------------------------------------------------------------------------
// 256x256 pipelined GEMM (ring-4, counted vmcnt), optional fused RoPE.
// ROPE: for output blocks with n0 < 2048 (q,k regions of the fused qkv),
// apply rotation in-register at the epilogue: pairs (i, i+32) of a head live
// in fragments (nt, nt+2) of the SAME thread (col = wn + nt*16 + c).
// EPI: 0 = bf16 store; 1 = bf16 relu(v+bias).
// ---------------------------------------------------------------------------
template <int EPI, bool ROPE>
__global__ __launch_bounds__(512, 2) void gemm256p(
    const __bf16* __restrict__ A, const __bf16* __restrict__ Bt,
    const float* __restrict__ bias, const float2* __restrict__ tab,
    __bf16* __restrict__ Cb, int M, int N, int K) {
  extern __shared__ char sm[];
  const int t = threadIdx.x, lane = t & 63, w = t >> 6;
  const int c = lane & 15, g = lane >> 4;
  const int nwg = gridDim.x * gridDim.y;
  const int wgid = blockIdx.y * gridDim.x + blockIdx.x;
  const int swz = (wgid & 7) * (nwg >> 3) + (wgid >> 3);
  const int m0 = (swz / gridDim.x) * 256, n0 = (swz % gridDim.x) * 256;
  const int wm = (w >> 2) * 128, wn = (w & 3) * 64;

  f32x4 acc[8][4] = {};
  const int nk = K >> 5;

  auto stage = [&](int buf, int kt) {
    const int k0 = kt << 5;
    char* base = sm + buf * 32768;
#pragma unroll
    for (int r = 0; r < 2; ++r) {
      int o = ((r * 8 + w) << 10) + (lane << 4);
      int rp = o >> 7;
      int u = (o >> 4) & 7;
      int l = u ^ (rp & 7);
      int mr = rp * 2 + (l >> 2);
      int kk = (l & 3) * 8;
      async16(base + o, A + (size_t)(m0 + mr) * K + k0 + kk);
      async16(base + 16384 + o, Bt + (size_t)(n0 + mr) * K + k0 + kk);
    }
  };

  auto body = [&](auto vmc, int tt, bool dostage) {
    if (dostage) stage((tt + 3) & 3, tt + 3);
    asm volatile("s_waitcnt vmcnt(%0)" ::"n"(decltype(vmc)::v) : "memory");
    __builtin_amdgcn_s_barrier();
    asm volatile("" ::: "memory");
    const char* Ab = sm + (tt & 3) * 32768;
    const char* Bb = Ab + 16384;
    bf16x8 aq[8], bq[4];
#pragma unroll
    for (int nt = 0; nt < 4; ++nt) {
      int row = wn + nt * 16 + c;
      int rp = row >> 1;
      int u = ((row & 1) * 4 + g) ^ (rp & 7);
      bq[nt] = *(const bf16x8*)(Bb + rp * 128 + u * 16);
    }
#pragma unroll
    for (int i = 0; i < 8; ++i) {
      int row = wm + i * 16 + c;
      int rp = row >> 1;
      int u = ((row & 1) * 4 + g) ^ (rp & 7);
      aq[i] = *(const bf16x8*)(Ab + rp * 128 + u * 16);
    }
    __builtin_amdgcn_s_setprio(1);
#pragma unroll
    for (int i = 0; i < 8; ++i)
#pragma unroll
      for (int nt = 0; nt < 4; ++nt)
        acc[i][nt] = __builtin_amdgcn_mfma_f32_16x16x32_bf16(
            aq[i], bq[nt], acc[i][nt], 0, 0, 0);
    __builtin_amdgcn_s_setprio(0);
    __builtin_amdgcn_s_barrier();
    asm volatile("" ::: "memory");
  };

  stage(0, 0);
  stage(1, 1);
  stage(2, 2);
  int tt = 0;
  for (; tt < nk - 3; ++tt) body(VMC<12>{}, tt, true);
  body(VMC<8>{}, tt, false); ++tt;
  body(VMC<4>{}, tt, false); ++tt;
  body(VMC<0>{}, tt, false);

  // fused RoPE on q,k blocks (n0 < 2048), in-register
  if (ROPE && n0 < 2048) {
#pragma unroll
    for (int i = 0; i < 8; ++i)
#pragma unroll
      for (int r = 0; r < 4; ++r) {
        int s = (m0 + wm + i * 16 + g * 4 + r) & (SLEN - 1);
        float2 t0 = tab[s * 32 + c];
        float2 t1 = tab[s * 32 + 16 + c];
        float q0 = acc[i][0][r], q2 = acc[i][2][r];
        acc[i][0][r] = q0 * t0.x - q2 * t0.y;
        acc[i][2][r] = q2 * t0.x + q0 * t0.y;
        float q1 = acc[i][1][r], q3 = acc[i][3][r];
        acc[i][1][r] = q1 * t1.x - q3 * t1.y;
        acc[i][3][r] = q3 * t1.x + q1 * t1.y;
      }
  }

#pragma unroll
  for (int i = 0; i < 8; ++i)
#pragma unroll
    for (int nt = 0; nt < 4; ++nt)
#pragma unroll
      for (int r = 0; r < 4; ++r) {
        int row = m0 + wm + i * 16 + g * 4 + r;
        int col = n0 + wn + nt * 16 + c;
        float v = acc[i][nt][r];
        size_t idx = (size_t)row * N + col;
        if constexpr (EPI == 0) {
          Cb[idx] = (__bf16)v;
        } else {
          v += bias[col];
          Cb[idx] = (__bf16)fmaxf(v, 0.f);
        }
      }
}

// ---------------------------------------------------------------------------
// GEMM 128x128 (MLP2/WO): EPI 2 = f32 out = xres+v+bias; 3 = out += mask*v
// ---------------------------------------------------------------------------
template <int EPI>
__global__ __launch_bounds__(256, 3) void gemm_bt(
    const __bf16* __restrict__ A, const __bf16* __restrict__ Bt,
    const float* __restrict__ bias, const float* __restrict__ xres,
    const float* __restrict__ maskp, __bf16* __restrict__ Cb,
    float* __restrict__ Cf, int M, int N, int K) {
  __shared__ char smem[32768];
  char* As = smem;
  char* Bs = smem + 16384;
  const int t = threadIdx.x, lane = t & 63, w = t >> 6;
  const int nwg = gridDim.x * gridDim.y;
  const int wgid = blockIdx.y * gridDim.x + blockIdx.x;
  const int swz = (wgid & 7) * (nwg >> 3) + (wgid >> 3);
  const int m0 = (swz / gridDim.x) * 128, n0 = (swz % gridDim.x) * 128;
  const int wm = (w >> 1) * 64, wn = (w & 1) * 64;
  f32x4 acc[4][4] = {};
  const int nk = K >> 6;
  for (int kt = 0; kt < nk; ++kt) {
    const int k0 = kt << 6;
#pragma unroll
    for (int rd = 0; rd < 4; ++rd) {
      int o = ((rd * 4 + w) << 10) + (lane << 4);
      int row = o >> 7;
      int us = ((o >> 4) & 7) ^ (row & 7);
      async16(As + o, A + (size_t)(m0 + row) * K + k0 + us * 8);
      async16(Bs + o, Bt + (size_t)(n0 + row) * K + k0 + us * 8);
    }
    __syncthreads();
#pragma unroll
    for (int ks = 0; ks < 2; ++ks) {
      bf16x8 af[4], bfr[4];
#pragma unroll
      for (int mt = 0; mt < 4; ++mt) {
        int row = wm + mt * 16 + (lane & 15);
        int u = (ks * 4 + (lane >> 4)) ^ (row & 7);
        af[mt] = *(const bf16x8*)(As + row * 128 + u * 16);
      }
#pragma unroll
      for (int nt = 0; nt < 4; ++nt) {
        int row = wn + nt * 16 + (lane & 15);
        int u = (ks * 4 + (lane >> 4)) ^ (row & 7);
        bfr[nt] = *(const bf16x8*)(Bs + row * 128 + u * 16);
      }
#pragma unroll
      for (int mt = 0; mt < 4; ++mt)
#pragma unroll
        for (int nt = 0; nt < 4; ++nt)
          acc[mt][nt] = __builtin_amdgcn_mfma_f32_16x16x32_bf16(
              af[mt], bfr[nt], acc[mt][nt], 0, 0, 0);
    }
    __syncthreads();
  }
#pragma unroll
  for (int mt = 0; mt < 4; ++mt)
#pragma unroll
    for (int nt = 0; nt < 4; ++nt)
#pragma unroll
      for (int r = 0; r < 4; ++r) {
        int row = m0 + wm + mt * 16 + ((lane >> 4) << 2) + r;
        int col = n0 + wn + nt * 16 + (lane & 15);
        float v = acc[mt][nt][r];
        size_t idx = (size_t)row * N + col;
        if constexpr (EPI == 2) {
          Cf[idx] = xres[idx] + v + bias[col];
        } else {
          Cf[idx] += maskp[row] * v;
        }
      }
}

// ---------------------------------------------------------------------------
// V scatter: regs -> swizzled Vt[d][kj] LDS
// ---------------------------------------------------------------------------
__device__ __forceinline__ void scatterV(char* Vdst, int w, int lane,
                                         float4 va, float4 vb) {
  union { float4 f; __bf16 bv[8]; } u0, u1;
  u0.f = va; u1.f = vb;
#pragma unroll
  for (int j = 0; j < 8; ++j) {
    int d = w * 8 + j;
    int by = d * 128 + (((lane >> 3) ^ (d & 7)) << 4) + ((lane & 7) << 1);
    *(__bf16*)(Vdst + by) = u0.bv[j];
    int d2 = d + 32;
    int by2 = d2 * 128 + (((lane >> 3) ^ (d2 & 7)) << 4) + ((lane & 7) << 1);
    *(__bf16*)(Vdst + by2) = u1.bv[j];
  }
}

// ---------------------------------------------------------------------------
// Flash attention, causal, swapped QK^T, in-lane softmax. Uniform q-tile
// pairs. XCD bh-grouping: the 8 same-bh blocks (sharing one 512KB K/V set)
// get the same blockIdx.x (= XCD under round-robin dispatch), so each XCD's
// L2 holds 8 bh x 512KB = 4MB of K/V (exactly fits) instead of 32MB thrash.
// bh = blockIdx.x*8 + (blockIdx.y&7), qtpair = blockIdx.y>>3 (bijective).
// ---------------------------------------------------------------------------
__global__ __launch_bounds__(256, 3) void attn_kernel(const __bf16* __restrict__ qkv,
                                                      __bf16* __restrict__ ctx) {
  __shared__ char sm[32768];
  const int t = threadIdx.x, lane = t & 63, w = t >> 6;
  const int c = lane & 15, g = lane >> 4, g4 = g * 4;
  const int bh = (int)blockIdx.x * 8 + ((int)blockIdx.y & 7);
  const int qp = (int)blockIdx.y >> 3;
  const int h = bh & 15, b = bh >> 4;
  const size_t tokbase = (size_t)b * SLEN;
  const __bf16* qg = qkv + tokbase * 3072 + h * 64;
  const __bf16* kg = qg + 1024;
  const __bf16* vg = qg + 2048;
  const float SCL = 0.125f * 1.44269504f;  // 1/sqrt(64) * log2(e)
  char* Ps = sm + (w << 12);
  char* Ks = sm + 16384;
  char* Vs = sm + 24576;

  for (int ph = 0; ph < 2; ++ph) {
    const int qt = ph == 0 ? qp : 15 - qp;
    const int q0 = qt * 128;
#pragma unroll
    for (int rd = 0; rd < 4; ++rd) {
      int o = ((rd * 4 + w) << 10) + (lane << 4);
      int row = o >> 7;
      int us = ((o >> 4) & 7) ^ (row & 7);
      async16(sm + o, qg + (size_t)(q0 + row) * 3072 + us * 8);
    }
    __syncthreads();
    bf16x8 qb[2][2];
#pragma unroll
    for (int mt = 0; mt < 2; ++mt)
#pragma unroll
      for (int ks = 0; ks < 2; ++ks) {
        int row = w * 32 + mt * 16 + c;
        int u = (ks * 4 + g) ^ (row & 7);
        qb[mt][ks] = *(const bf16x8*)(sm + row * 128 + u * 16);
      }

    float m_run[2] = {-1e30f, -1e30f}, l_run[2] = {0.f, 0.f};
    f32x4 o_acc[2][4] = {};
    const int nkt = (q0 + 128) >> 6;
    const int wrow0 = q0 + w * 32;

    for (int kt = 0; kt < nkt; ++kt) {
      const int k0 = kt << 6;
#pragma unroll
      for (int rd = 0; rd < 2; ++rd) {
        int o = ((rd * 4 + w) << 10) + (lane << 4);
        int row = o >> 7;
        int us = ((o >> 4) & 7) ^ (row & 7);
        async16(Ks + o, kg + (size_t)(k0 + row) * 3072 + us * 8);
      }
      {
        float4 va = *(const float4*)(vg + (size_t)(k0 + lane) * 3072 + w * 8);
        float4 vb2 = *(const float4*)(vg + (size_t)(k0 + lane) * 3072 + w * 8 + 32);
        scatterV(Vs, w, lane, va, vb2);
      }
      __syncthreads();
      if (k0 <= wrow0 + 31) {
        f32x4 st[4][2] = {};
        __builtin_amdgcn_s_setprio(1);
#pragma unroll
        for (int ks = 0; ks < 2; ++ks) {
          bf16x8 ka[4];
#pragma unroll
          for (int nt = 0; nt < 4; ++nt) {
            int row = nt * 16 + c;
            int u = (ks * 4 + g) ^ (row & 7);
            ka[nt] = *(const bf16x8*)(Ks + row * 128 + u * 16);
          }
#pragma unroll
          for (int nt = 0; nt < 4; ++nt)
#pragma unroll
            for (int mt = 0; mt < 2; ++mt)
              st[nt][mt] = __builtin_amdgcn_mfma_f32_16x16x32_bf16(
                  ka[nt], qb[mt][ks], st[nt][mt], 0, 0, 0);
        }
        __builtin_amdgcn_s_setprio(0);
        const bool needmask = (k0 + 63) > wrow0;
#pragma unroll
        for (int mt = 0; mt < 2; ++mt) {
          float mx = -1e30f;
          if (needmask) {
            int qglob = wrow0 + mt * 16 + c;
#pragma unroll
            for (int nt = 0; nt < 4; ++nt)
#pragma unroll
              for (int r = 0; r < 4; ++r) {
                float sv = st[nt][mt][r] * SCL;
                if (k0 + nt * 16 + g4 + r > qglob) sv = -1e30f;
                st[nt][mt][r] = sv;
                mx = fmaxf(mx, sv);
              }
          } else {
#pragma unroll
            for (int nt = 0; nt < 4; ++nt)
#pragma unroll
              for (int r = 0; r < 4; ++r) {
                float sv = st[nt][mt][r] * SCL;
                st[nt][mt][r] = sv;
                mx = fmaxf(mx, sv);
              }
          }
          mx = fmaxf(mx, __shfl_xor(mx, 16));
          mx = fmaxf(mx, __shfl_xor(mx, 32));
          const bool skip = __all(mx - m_run[mt] <= 8.f) != 0;
          float mnew = skip ? m_run[mt] : fmaxf(m_run[mt], mx);
          float rs = 0.f;
#pragma unroll
          for (int nt = 0; nt < 4; ++nt)
#pragma unroll
            for (int r = 0; r < 4; ++r) {
              float p = __builtin_amdgcn_exp2f(st[nt][mt][r] - mnew);
              st[nt][mt][r] = p;
              rs += p;
            }
          rs += __shfl_xor(rs, 16);
          rs += __shfl_xor(rs, 32);
          if (skip) {
            l_run[mt] += rs;
          } else {
            float fac = __builtin_amdgcn_exp2f(m_run[mt] - mnew);
            m_run[mt] = mnew;
            l_run[mt] = l_run[mt] * fac + rs;
#pragma unroll
            for (int r = 0; r < 4; ++r) {
              float fr = __shfl(fac, g * 20 + r);
#pragma unroll
              for (int dt = 0; dt < 4; ++dt) o_acc[mt][dt][r] *= fr;
            }
          }
          int rowq = mt * 16 + c;
          int rbase = rowq * 128 + 8 * (g & 1);
#pragma unroll
          for (int nt = 0; nt < 4; ++nt) {
            int us = (2 * nt + (g >> 1)) ^ (c & 7);
            union { uint2 v; __bf16 bb[4]; } pp;
            pp.bb[0] = (__bf16)st[nt][mt][0]; pp.bb[1] = (__bf16)st[nt][mt][1];
            pp.bb[2] = (__bf16)st[nt][mt][2]; pp.bb[3] = (__bf16)st[nt][mt][3];
            *(uint2*)(Ps + rbase + us * 16) = pp.v;
          }
        }
        __builtin_amdgcn_s_setprio(1);
#pragma unroll
        for (int ks = 0; ks < 2; ++ks) {
          bf16x8 pa[2], vb[4];
#pragma unroll
          for (int mt = 0; mt < 2; ++mt) {
            int row = mt * 16 + c;
            int u = (ks * 4 + g) ^ (row & 7);
            pa[mt] = *(const bf16x8*)(Ps + row * 128 + u * 16);
          }
#pragma unroll
          for (int dt = 0; dt < 4; ++dt) {
            int row = dt * 16 + c;
            int u = (ks * 4 + g) ^ (row & 7);
            vb[dt] = *(const bf16x8*)(Vs + row * 128 + u * 16);
          }
#pragma unroll
          for (int mt = 0; mt < 2; ++mt)
#pragma unroll
            for (int dt = 0; dt < 4; ++dt)
              o_acc[mt][dt] = __builtin_amdgcn_mfma_f32_16x16x32_bf16(
                  pa[mt], vb[dt], o_acc[mt][dt], 0, 0, 0);
        }
        __builtin_amdgcn_s_setprio(0);
      }
      __syncthreads();
    }
#pragma unroll
    for (int mt = 0; mt < 2; ++mt)
#pragma unroll
      for (int r = 0; r < 4; ++r) {
        float lr = __shfl(l_run[mt], g * 20 + r);
        float inv = 1.f / lr;
        int tokr = q0 + w * 32 + mt * 16 + g4 + r;
#pragma unroll
        for (int dt = 0; dt < 4; ++dt) {
          int d = dt * 16 + c;
          ctx[(tokbase + tokr) * DDIM + h * 64 + d] =
              (__bf16)(o_acc[mt][dt][r] * inv);
        }
      }
  }
}

// ---------------------------------------------------------------------------
// aux loss: (mean(probs) - 0.2)^2
// ---------------------------------------------------------------------------
__global__ __launch_bounds__(256) void aux_kernel(const float* __restrict__ probsp,
                                                  float* __restrict__ outp) {
  const int t = threadIdx.x;
  float sum = 0.f;
  for (int i = t; i < NTOK; i += 256) sum += probsp[i];
#pragma unroll
  for (int d = 32; d; d >>= 1) sum += __shfl_down(sum, d);
  __shared__ float ws4[4];
  if ((t & 63) == 0) ws4[t >> 6] = sum;
  __syncthreads();
  if (t == 0) {
    float m = (ws4[0] + ws4[1] + ws4[2] + ws4[3]) * (1.f / NTOK) - 0.2f;
    outp[0] = m * m;
  }
}

// ---------------------------------------------------------------------------
extern "C" void kernel_launch(void* const* d_in, const int* in_sizes, int n_in,
                              void* d_out, int out_size, void* d_ws, size_t ws_size,
                              hipStream_t stream) {
  const float* x      = (const float*)d_in[0];
  const float* gate_w = (const float*)d_in[1];
  const float* gate_b = (const float*)d_in[2];
  const float* wq     = (const float*)d_in[3];
  const float* wk     = (const float*)d_in[4];
  const float* wv     = (const float*)d_in[5];
  const float* wo     = (const float*)d_in[6];
  const float* conv_w = (const float*)d_in[7];
  const float* conv_b = (const float*)d_in[8];
  const float* mlp_w1 = (const float*)d_in[9];
  const float* mlp_b1 = (const float*)d_in[10];
  const float* mlp_w2 = (const float*)d_in[11];
  const float* mlp_b2 = (const float*)d_in[12];
  float* out = (float*)d_out;

  char* ws = (char*)d_ws;
  const size_t MB = 1ull << 20;
  __bf16* xb     = (__bf16*)(ws + 0);
  __bf16* xcb    = (__bf16*)(ws + 16 * MB);
  __bf16* ctx    = (__bf16*)(ws + 16 * MB);    // overlays xcb
  __bf16* wqkv_t = (__bf16*)(ws + 32 * MB);
  __bf16* wo_t   = (__bf16*)(ws + 38 * MB);
  __bf16* w1_t   = (__bf16*)(ws + 40 * MB);
  __bf16* w2_t   = (__bf16*)(ws + 48 * MB);
  float*  maskp  = (float*)(ws + 56 * MB);
  float*  probsp = (float*)(ws + 56 * MB + 65536);
  float2* ropetab= (float2*)(ws + 56 * MB + 131072);  // 512KB
  __bf16* h1     = (__bf16*)(ws + 57 * MB);
  __bf16* qkv    = (__bf16*)(ws + 57 * MB);    // overlays h1

  prep_kernel<<<NTOK, 256, 0, stream>>>(x, gate_w, gate_b, conv_w, conv_b,
                                        xb, xcb, maskp, probsp);
  tabgen_kernel<<<256, 256, 0, stream>>>(ropetab);
  tcast_kernel<<<dim3(16, 16), 256, 0, stream>>>(wq, wqkv_t, 1024, 1024);
  tcast_kernel<<<dim3(16, 16), 256, 0, stream>>>(wk, wqkv_t + 1024 * 1024, 1024, 1024);
  tcast_kernel<<<dim3(16, 16), 256, 0, stream>>>(wv, wqkv_t + 2048 * 1024, 1024, 1024);
  tcast_kernel<<<dim3(16, 16), 256, 0, stream>>>(wo, wo_t, 1024, 1024);
  tcast_kernel<<<dim3(64, 16), 256, 0, stream>>>(mlp_w1, w1_t, 1024, 4096);
  tcast_kernel<<<dim3(16, 64), 256, 0, stream>>>(mlp_w2, w2_t, 4096, 1024);

  // Reflexive (MLP) stream first so h1 region can be reused by qkv.
  gemm256p<1, false><<<dim3(16, 32), 512, 131072, stream>>>(
      xcb, w1_t, mlp_b1, nullptr, h1, NTOK, MLPD, DDIM);
  gemm_bt<2><<<dim3(8, 64), 256, 0, stream>>>(h1, w2_t, mlp_b2, x, nullptr,
                                              nullptr, out, NTOK, DDIM, MLPD);
  // Contextual stream (RoPE fused into the QKV epilogue).
  gemm256p<0, true><<<dim3(12, 32), 512, 131072, stream>>>(
      xb, wqkv_t, nullptr, ropetab, qkv, NTOK, 3072, DDIM);
  attn_kernel<<<dim3(8, 64), 256, 0, stream>>>(qkv, ctx);
  gemm_bt<3><<<dim3(8, 64), 256, 0, stream>>>(ctx, wo_t, nullptr, nullptr, maskp,
                                              nullptr, out, NTOK, DDIM, DDIM);
  aux_kernel<<<1, 256, 0, stream>>>(probsp, out + (size_t)(out_size - 1));
}